// Round 3
// baseline (338.685 us; speedup 1.0000x reference)
//
#include <hip/hip_runtime.h>

typedef __bf16 bf16x8 __attribute__((ext_vector_type(8)));
typedef float f32x4 __attribute__((ext_vector_type(4)));
typedef unsigned short us8 __attribute__((ext_vector_type(8)));

#define PI_F 3.14159265358979323846f

__device__ __forceinline__ unsigned short f2bf(float f) {
    unsigned u = __float_as_uint(f);
    u += 0x7FFFu + ((u >> 16) & 1u);   // RNE
    return (unsigned short)(u >> 16);
}
__device__ __forceinline__ float bf2f(unsigned short h) {
    return __uint_as_float(((unsigned)h) << 16);
}

__device__ __forceinline__ void async16(const void* g, void* l) {
    __builtin_amdgcn_global_load_lds(
        (const __attribute__((address_space(1))) unsigned int*)g,
        (__attribute__((address_space(3))) unsigned int*)l, 16, 0, 0);
}

// ---------------------------------------------------------------------------
// Merged weight prep.
// idx < 1M : W1b[(k*8+h)*1024 + d] = bf16( W_proj[h,k,d] * cos(pi*freq[h,k]) )
// else     : Wob[n*1024 + (k*8+h)] = bf16( out_W[n, h*128+k] )
__global__ __launch_bounds__(256) void prep_k(const float* __restrict__ W,
                                              const float* __restrict__ fr,
                                              const float* __restrict__ Wo,
                                              unsigned short* __restrict__ W1b,
                                              unsigned short* __restrict__ Wob) {
    int idx = blockIdx.x * 256 + threadIdx.x;      // 2M
    if (idx < (1 << 20)) {
        int n = idx >> 10, d = idx & 1023;
        int k = n >> 3, h = n & 7;
        float c = cosf(fr[h * 128 + k] * PI_F);
        W1b[idx] = f2bf(W[((h * 128 + k) << 10) + d] * c);
    } else {
        int i2 = idx - (1 << 20);
        int n = i2 >> 10, dp = i2 & 1023;
        int k = dp >> 3, h = dp & 7;
        Wob[i2] = f2bf(Wo[(n << 10) + h * 128 + k]);
    }
}

// ---------------------------------------------------------------------------
// x -> bf16 cast + per-(b,d) partial column sums via PLAIN stores.
__global__ __launch_bounds__(256) void xbar_cast(const float* __restrict__ x,
                                                 unsigned short* __restrict__ xb,
                                                 float* __restrict__ part) {
    int bid = blockIdx.x;            // 1024
    int b = bid >> 8;
    int s0 = (bid & 255) * 16;
    int t = threadIdx.x;             // d4 index
    float a0 = 0.f, a1 = 0.f, a2 = 0.f, a3 = 0.f;
    for (int i = 0; i < 16; ++i) {
        long row = (long)b * 4096 + s0 + i;
        float4 v = ((const float4*)x)[row * 256 + t];
        a0 += v.x; a1 += v.y; a2 += v.z; a3 += v.w;
        ushort4 u;
        u.x = f2bf(v.x); u.y = f2bf(v.y); u.z = f2bf(v.z); u.w = f2bf(v.w);
        ((ushort4*)xb)[row * 256 + t] = u;
    }
    float4 p; p.x = a0; p.y = a1; p.z = a2; p.w = a3;
    ((float4*)part)[bid * 256 + t] = p;
}

// Reduce part[1024][1024] -> xbar[4][1024]. 32 blocks, fully coalesced.
__global__ __launch_bounds__(256) void xbar_r(const float* __restrict__ part,
                                              float* __restrict__ xbar) {
    __shared__ float sl[256];
    int blk = blockIdx.x;            // 32 = b*8 + dgrp
    int b = blk >> 3, dgrp = blk & 7;
    int t = threadIdx.x;
    int col = dgrp * 128 + (t & 127);
    int ih = t >> 7;
    float s = 0.f;
    for (int i = 0; i < 128; ++i) {
        int cb = b * 256 + ih * 128 + i;
        s += part[cb * 1024 + col];
    }
    sl[t] = s;
    __syncthreads();
    if (t < 128) xbar[b * 1024 + col] = sl[t] + sl[t + 128];
}

// ---------------------------------------------------------------------------
// summary[b,h,k] = (1/S) * dot(xbar[b,:], W_proj[h,k,:]) * cos(pi*freq[h,k])
__global__ __launch_bounds__(256) void summary_k(const float* __restrict__ xbar,
                                                 const float* __restrict__ W,
                                                 const float* __restrict__ fr,
                                                 float* __restrict__ summary) {
    int wave = (blockIdx.x * 256 + threadIdx.x) >> 6;   // 0..4095 = b*1024+h*128+k
    int lane = threadIdx.x & 63;
    int b = wave >> 10, hk = wave & 1023;
    int h = hk >> 7, k = hk & 127;
    const float* wrow = &W[(h * 128 + k) << 10];
    const float* xrow = &xbar[b << 10];
    float s = 0.f;
    for (int d = lane; d < 1024; d += 64) s += xrow[d] * wrow[d];
    for (int off = 32; off; off >>= 1) s += __shfl_down(s, off);
    if (lane == 0) {
        float c = cosf(fr[h * 128 + k] * PI_F);
        summary[wave] = s * c * (1.0f / 4096.0f);
    }
}

// ---------------------------------------------------------------------------
// pol -> normalize -> dots -> gelu MLP -> softplus -> impedance & coef. 1 block.
__global__ __launch_bounds__(256) void imp_k(const float* __restrict__ summary,
                                             const float* __restrict__ pol_W,
                                             const float* __restrict__ pol_b,
                                             const float* __restrict__ imp_W1,
                                             const float* __restrict__ imp_b1,
                                             const float* __restrict__ imp_W2,
                                             const float* __restrict__ imp_b2,
                                             float* __restrict__ coef_out,
                                             float* __restrict__ imp_out) {
    __shared__ float pol[4][8][32];
    __shared__ float rn[32];
    int t = threadIdx.x;
    for (int o = t; o < 1024; o += 256) {
        int b = o >> 8, h = (o >> 5) & 7, p = o & 31;
        const float* srow = &summary[(b * 8 + h) * 128];
        const float* wrow = &pol_W[(h * 32 + p) * 128];
        float acc = pol_b[h * 32 + p];
        for (int k = 0; k < 128; ++k) acc += srow[k] * wrow[k];
        pol[b][h][p] = tanhf(acc);
    }
    __syncthreads();
    if (t < 32) {
        int b = t >> 3, h = t & 7;
        float ss = 0.f;
        for (int p = 0; p < 32; ++p) { float v = pol[b][h][p]; ss += v * v; }
        rn[t] = 1.0f / fmaxf(sqrtf(ss), 1e-12f);
    }
    __syncthreads();
    {
        int b = t >> 6, i = (t >> 3) & 7, j = t & 7;
        float d = 0.f;
        for (int p = 0; p < 32; ++p) d += pol[b][i][p] * pol[b][j][p];
        d *= rn[b * 8 + i] * rn[b * 8 + j];
        float s = imp_b2[0];
        for (int c = 0; c < 16; ++c) {
            float z = d * imp_W1[c] + imp_b1[c];
            float gl = 0.5f * z * (1.0f + erff(z * 0.70710678118654752f));
            s += gl * imp_W2[c];
        }
        float sp = fmaxf(s, 0.0f) + log1pf(expf(-fabsf(s)));   // softplus
        float impv = (i == j) ? 0.0f : sp;
        imp_out[t] = impv;
        coef_out[t] = (i == j) ? 0.0f : 0.1f / (1.0f + impv);
    }
}

// ---------------------------------------------------------------------------
// ===== 128x128 GEMM core: counted-vmcnt ring-4 schedule, 2 blocks/CU =======
//
// Rounds 1-2 (256x256, 128KB LDS, 1 block/CU) pinned MfmaUtil at 22-24%
// across two different phase schedules: with one block per CU every
// barrier/vmcnt idles the whole CU.  This core keeps the ring-4 counted
// schedule but at 128x128 / 4 waves / 64KB LDS -> 2 resident blocks per CU,
// restoring inter-block overlap (m114) on top of counted vmcnt (T4).
//
// 256 thr = 4 waves (wm=wid>>1, wn=wid&1); per-wave out 64x64, acc[4][4].
// LDS 64KB = per matrix 4 ring slots of 8KB; slot = one 32-k half-tile
// (128 rows x 32 k).  Phase g (g=0..31): reads slot g&3, stages half g+2
// into slot (g+2)&3; ONE barrier per phase:
//   { issue 4x global_load_lds(half g+2); VMCNT(8); s_barrier;
//     8x ds_read_b128; 16x MFMA (setprio-wrapped) }
// Write(slot g+2) vs read(g-2) separated by 2 barriers even with drift;
// VMCNT(8) before the barrier guarantees every wave's half-g staging landed.
// Counted vmcnt never drains to 0 mid-loop (T4).
//
// LDS layout in a slot is DEFINED by the linear global_load_lds dest
// (dest = base + t*16): subtile s = 16 rows x 32 k contiguous 1KB; element
// (rowlow, kc16B) at s*1024 + kc*256 + rowlow*16.  Fragment read addr =
// subtile*1024 + (l>>4)*256 + (l&15)*16 -> lane-linear 1KB, conflict-free.
// ---------------------------------------------------------------------------
#define VMCNT(n) asm volatile("s_waitcnt vmcnt(" #n ")" ::: "memory")
#define SBAR() __builtin_amdgcn_s_barrier()

// XCD-contiguous swizzle for grid 1024 (128 row-blocks x 8 col-blocks):
// each XCD (n&7) gets a contiguous 16-row-band slab; cols iterate slowest.
// (Round-0 verified: FETCH 132->62 MB.)
__device__ __forceinline__ void swizzle_blk(int n, long& rowBase, long& colBase) {
    int xcd = n & 7, s = n >> 3;                 // s in 0..127
    rowBase = (long)(xcd * 16 + (s & 15)) * 128;
    colBase = (long)(s >> 4) * 128;
}

// Stage one 128-row x 32-k half-tile (8KB): rows 0..63 then 64..127.
#define STG2(sPtr, dPtr, koff, slot)                                         \
    async16((sPtr) + (koff), (dPtr) + (slot) * 8192);                        \
    async16((sPtr) + (koff) + 131072, (dPtr) + (slot) * 8192 + 4096);

// One phase: stage half g+2, counted wait, barrier, 8 reads + 16 MFMA.
#define PH(p, DO_ST, KOFF, VM)                                               \
    {                                                                        \
        if (DO_ST) {                                                         \
            STG2(sA, stDstA, (KOFF), ((p) + 2) & 3)                          \
            STG2(sB, stDstB, (KOFF), ((p) + 2) & 3)                          \
        }                                                                    \
        VM;                                                                  \
        SBAR();                                                              \
        const char* pA = rdA + ((p) & 3) * 8192;                             \
        const char* pB = rdB + ((p) & 3) * 8192;                             \
        bf16x8 af[4], bv[4];                                                 \
        _Pragma("unroll") for (int i_ = 0; i_ < 4; ++i_)                     \
            af[i_] = *(const bf16x8*)(pA + i_ * 1024);                       \
        _Pragma("unroll") for (int i_ = 0; i_ < 4; ++i_)                     \
            bv[i_] = *(const bf16x8*)(pB + i_ * 1024);                       \
        __builtin_amdgcn_s_setprio(1);                                       \
        _Pragma("unroll") for (int mi = 0; mi < 4; ++mi)                     \
            _Pragma("unroll") for (int ni = 0; ni < 4; ++ni)                 \
                acc[mi][ni] = __builtin_amdgcn_mfma_f32_16x16x32_bf16(       \
                    af[mi], bv[ni], acc[mi][ni], 0, 0, 0);                   \
        __builtin_amdgcn_s_setprio(0);                                       \
    }

__device__ __forceinline__ void gemm4_core(const char* gAB, const char* gBB,
                                           char* smem, const int t,
                                           f32x4 acc[4][4]) {
    const int l = t & 63, wid = t >> 6;          // 4 waves
    const int wm = wid >> 1, wn = wid & 1;
    // staging source: row = wid*16 + (t&15), k-chunk = ((t>>4)&3)*16B
    const long stOff = (long)((wid << 4) + (t & 15)) * 2048 + ((t >> 4) & 3) * 16;
    const char* sA = gAB + stOff;
    const char* sB = gBB + stOff;
    char* As = smem;                 // 4 slots x 8KB
    char* Bs = smem + 32768;         // 4 slots x 8KB
    char* stDstA = As + wid * 1024;  // + slot*8192 (+4096 rows 64..127)
    char* stDstB = Bs + wid * 1024;
    const char* rdA = As + wm * 4096 + (l >> 4) * 256 + (l & 15) * 16;
    const char* rdB = Bs + wn * 4096 + (l >> 4) * 256 + (l & 15) * 16;

    // Prologue: stage halves 0 and 1 (8 loads in flight).
    STG2(sA, stDstA, 0, 0)
    STG2(sB, stDstB, 0, 0)
    STG2(sA, stDstA, 64, 1)
    STG2(sB, stDstB, 64, 1)

    int kb = 128;                    // byte offset of half 2
    for (int grp = 0; grp < 7; ++grp) {   // phases 0..27
        PH(0, true, kb, VMCNT(8))
        PH(1, true, kb + 64, VMCNT(8))
        PH(2, true, kb + 128, VMCNT(8))
        PH(3, true, kb + 192, VMCNT(8))
        kb += 256;
    }
    PH(0, true, 1920, VMCNT(8))      // g=28, stages half 30
    PH(1, true, 1984, VMCNT(8))      // g=29, stages half 31
    PH(2, false, 0, VMCNT(4))        // g=30 (drain stage 30)
    PH(3, false, 0, VMCNT(0))        // g=31 (drain stage 31)
}

// ---------------------------------------------------------------------------
// GEMM1 + fused head-mix epilogue (round-0 proven layout).  Columns are
// (k,h)-interleaved, mix group = 8 consecutive cols.  8 passes x 16-row
// slab (16x132 f32 = 8.45KB aliased over A-slot 0; safe: last phases read
// slots 2/3 only, and every wave has passed barrier(31)).
__global__ __launch_bounds__(256, 2) void gemm1_mix(
    const unsigned short* __restrict__ A, const unsigned short* __restrict__ B,
    const float* __restrict__ coef, const int* __restrict__ causal,
    unsigned short* __restrict__ C) {
    __shared__ char smem[65536];
    __shared__ float cfs[64];
    const int t = threadIdx.x;
    long rowBase, colBase;
    swizzle_blk(blockIdx.x, rowBase, colBase);
    const int b = (int)(rowBase >> 12);
    if (t < 64) cfs[t] = coef[b * 64 + t];
    const int causalv = causal[0];

    f32x4 acc[4][4] = {};
    gemm4_core((const char*)A + rowBase * 2048, (const char*)B + colBase * 2048,
               smem, t, acc);

    const int l = t & 63, wid = t >> 6;
    const int wm = wid >> 1, wn = wid & 1;
    const int q = l >> 4, c16 = l & 15;
    float* mixt = (float*)smem;      // 16 x 132 f32
    const int r16 = t >> 4, kg = t & 15;
#pragma unroll
    for (int p = 0; p < 8; ++p) {
        if (wm == (p >> 2)) {
            int mi = p & 3;
#pragma unroll
            for (int ni = 0; ni < 4; ++ni)
#pragma unroll
                for (int r = 0; r < 4; ++r)
                    mixt[(q * 4 + r) * 132 + wn * 64 + ni * 16 + c16] = acc[mi][ni][r];
        }
        __syncthreads();
        const float* src = mixt + r16 * 132 + kg * 8;
        float v[8];
#pragma unroll
        for (int j = 0; j < 8; ++j) v[j] = src[j];
        long row = rowBase + p * 16 + r16;
        float scale = causalv ? (float)((row & 4095) + 1) * (1.0f / 4096.0f) : 1.0f;
        us8 o;
#pragma unroll
        for (int i = 0; i < 8; ++i) {
            float ts = 0.f;
#pragma unroll
            for (int j = 0; j < 8; ++j) ts += cfs[i * 8 + j] * v[j];
            o[i] = f2bf(v[i] + scale * ts);
        }
        *(us8*)(C + row * 1024 + colBase + kg * 8) = o;
        __syncthreads();
    }
}

// ---------------------------------------------------------------------------
// Plain GEMM (second projection): C = A @ B^T, bf16 out.
__global__ __launch_bounds__(256, 2) void gemm_bt(const unsigned short* __restrict__ A,
                                                  const unsigned short* __restrict__ B,
                                                  unsigned short* __restrict__ C) {
    __shared__ char smem[65536];
    const int t = threadIdx.x;
    long rowBase, colBase;
    swizzle_blk(blockIdx.x, rowBase, colBase);

    f32x4 acc[4][4] = {};
    gemm4_core((const char*)A + rowBase * 2048, (const char*)B + colBase * 2048,
               smem, t, acc);

    const int l = t & 63, wid = t >> 6;
    const int wm = wid >> 1, wn = wid & 1;
    const int q = l >> 4, c16 = l & 15;
#pragma unroll
    for (int mi = 0; mi < 4; ++mi) {
#pragma unroll
        for (int ni = 0; ni < 4; ++ni) {
            long col = colBase + wn * 64 + ni * 16 + c16;
            long row0 = rowBase + wm * 64 + mi * 16 + q * 4;
#pragma unroll
            for (int r = 0; r < 4; ++r)
                C[(row0 + r) * 1024 + col] = f2bf(acc[mi][ni][r]);
        }
    }
}

// ---------------------------------------------------------------------------
// LayerNorm over D=1024: y = ypre + out_b + x; out = (y-mu)/sqrt(var+eps)*g+b
__global__ __launch_bounds__(256) void ln_k(const unsigned short* __restrict__ ypre,
                                            const float* __restrict__ x,
                                            const float* __restrict__ outb,
                                            const float* __restrict__ gam,
                                            const float* __restrict__ bet,
                                            float* __restrict__ out) {
    int row = blockIdx.x;       // 16384
    int t = threadIdx.x;        // 256, 4 elems each
    long base = (long)row * 1024 + t * 4;
    ushort4 yp = *(const ushort4*)(ypre + base);
    float4 xv = *(const float4*)(x + base);
    float4 bv = *(const float4*)(outb + t * 4);
    float y0 = bf2f(yp.x) + xv.x + bv.x;
    float y1 = bf2f(yp.y) + xv.y + bv.y;
    float y2 = bf2f(yp.z) + xv.z + bv.z;
    float y3 = bf2f(yp.w) + xv.w + bv.w;
    float s = y0 + y1 + y2 + y3;
    float ss = y0 * y0 + y1 * y1 + y2 * y2 + y3 * y3;
    for (int off = 32; off; off >>= 1) {
        s += __shfl_down(s, off);
        ss += __shfl_down(ss, off);
    }
    __shared__ float red[8];
    int wv = t >> 6, ln = t & 63;
    if (ln == 0) { red[wv] = s; red[4 + wv] = ss; }
    __syncthreads();
    float S1 = red[0] + red[1] + red[2] + red[3];
    float S2 = red[4] + red[5] + red[6] + red[7];
    float mu = S1 * (1.0f / 1024.0f);
    float var = S2 * (1.0f / 1024.0f) - mu * mu;
    float rs = 1.0f / sqrtf(var + 1e-5f);
    float4 gv = *(const float4*)(gam + t * 4);
    float4 bb = *(const float4*)(bet + t * 4);
    float4 o;
    o.x = (y0 - mu) * rs * gv.x + bb.x;
    o.y = (y1 - mu) * rs * gv.y + bb.y;
    o.z = (y2 - mu) * rs * gv.z + bb.z;
    o.w = (y3 - mu) * rs * gv.w + bb.w;
    *(float4*)(out + base) = o;
}

// ---------------------------------------------------------------------------
extern "C" void kernel_launch(void* const* d_in, const int* in_sizes, int n_in,
                              void* d_out, int out_size, void* d_ws, size_t ws_size,
                              hipStream_t stream) {
    const float* x       = (const float*)d_in[0];
    const float* W_proj  = (const float*)d_in[1];
    const float* freqs   = (const float*)d_in[2];
    const float* pol_W   = (const float*)d_in[3];
    const float* pol_b   = (const float*)d_in[4];
    const float* imp_W1  = (const float*)d_in[5];
    const float* imp_b1  = (const float*)d_in[6];
    const float* imp_W2  = (const float*)d_in[7];
    const float* imp_b2  = (const float*)d_in[8];
    const float* out_W   = (const float*)d_in[9];
    const float* out_b   = (const float*)d_in[10];
    const float* ln_g    = (const float*)d_in[11];
    const float* ln_b    = (const float*)d_in[12];
    const int*   causal  = (const int*)d_in[13];
    float* out = (float*)d_out;

    char* ws = (char*)d_ws;
    unsigned short* xb      = (unsigned short*)(ws + 0);          // 32MB, reused as ypre
    unsigned short* merged  = (unsigned short*)(ws + 33554432);   // 32MB
    unsigned short* w1b     = (unsigned short*)(ws + 67108864);   // 2MB
    unsigned short* wob     = (unsigned short*)(ws + 69206016);   // 2MB
    float* xbar             = (float*)(ws + 71303168);            // 16KB
    float* summary          = (float*)(ws + 71319552);            // 16KB
    float* coef             = (float*)(ws + 71335936);            // 1KB
    float* part             = (float*)merged;                     // 4MB, dead before gemm1_mix
    unsigned short* ypre    = xb;

    prep_k<<<8192, 256, 0, stream>>>(W_proj, freqs, out_W, w1b, wob);
    xbar_cast<<<1024, 256, 0, stream>>>(x, xb, part);
    xbar_r<<<32, 256, 0, stream>>>(part, xbar);
    summary_k<<<1024, 256, 0, stream>>>(xbar, W_proj, freqs, summary);
    imp_k<<<1, 256, 0, stream>>>(summary, pol_W, pol_b, imp_W1, imp_b1,
                                 imp_W2, imp_b2, coef, out + 16777216);
    gemm1_mix<<<1024, 256, 0, stream>>>(xb, w1b, coef, causal, merged);
    gemm_bt<<<1024, 256, 0, stream>>>(merged, wob, ypre);
    ln_k<<<16384, 256, 0, stream>>>(ypre, x, out_b, ln_g, ln_b, out);
}

// Round 4
// 315.627 us; speedup vs baseline: 1.0731x; 1.0731x over previous
//
#include <hip/hip_runtime.h>

typedef __bf16 bf16x8 __attribute__((ext_vector_type(8)));
typedef float f32x4 __attribute__((ext_vector_type(4)));
typedef unsigned short us8 __attribute__((ext_vector_type(8)));

#define PI_F 3.14159265358979323846f

__device__ __forceinline__ unsigned short f2bf(float f) {
    unsigned u = __float_as_uint(f);
    u += 0x7FFFu + ((u >> 16) & 1u);   // RNE
    return (unsigned short)(u >> 16);
}
__device__ __forceinline__ float bf2f(unsigned short h) {
    return __uint_as_float(((unsigned)h) << 16);
}

__device__ __forceinline__ void async16(const void* g, void* l) {
    __builtin_amdgcn_global_load_lds(
        (const __attribute__((address_space(1))) unsigned int*)g,
        (__attribute__((address_space(3))) unsigned int*)l, 16, 0, 0);
}

// ---------------------------------------------------------------------------
// Merged weight prep.
// idx < 1M : W1b[(k*8+h)*1024 + d] = bf16( W_proj[h,k,d] * cos(pi*freq[h,k]) )
// else     : Wob[n*1024 + (k*8+h)] = bf16( out_W[n, h*128+k] )
__global__ __launch_bounds__(256) void prep_k(const float* __restrict__ W,
                                              const float* __restrict__ fr,
                                              const float* __restrict__ Wo,
                                              unsigned short* __restrict__ W1b,
                                              unsigned short* __restrict__ Wob) {
    int idx = blockIdx.x * 256 + threadIdx.x;      // 2M
    if (idx < (1 << 20)) {
        int n = idx >> 10, d = idx & 1023;
        int k = n >> 3, h = n & 7;
        float c = cosf(fr[h * 128 + k] * PI_F);
        W1b[idx] = f2bf(W[((h * 128 + k) << 10) + d] * c);
    } else {
        int i2 = idx - (1 << 20);
        int n = i2 >> 10, dp = i2 & 1023;
        int k = dp >> 3, h = dp & 7;
        Wob[i2] = f2bf(Wo[(n << 10) + h * 128 + k]);
    }
}

// ---------------------------------------------------------------------------
// x -> bf16 cast + per-(b,d) partial column sums via PLAIN stores.
__global__ __launch_bounds__(256) void xbar_cast(const float* __restrict__ x,
                                                 unsigned short* __restrict__ xb,
                                                 float* __restrict__ part) {
    int bid = blockIdx.x;            // 1024
    int b = bid >> 8;
    int s0 = (bid & 255) * 16;
    int t = threadIdx.x;             // d4 index
    float a0 = 0.f, a1 = 0.f, a2 = 0.f, a3 = 0.f;
    for (int i = 0; i < 16; ++i) {
        long row = (long)b * 4096 + s0 + i;
        float4 v = ((const float4*)x)[row * 256 + t];
        a0 += v.x; a1 += v.y; a2 += v.z; a3 += v.w;
        ushort4 u;
        u.x = f2bf(v.x); u.y = f2bf(v.y); u.z = f2bf(v.z); u.w = f2bf(v.w);
        ((ushort4*)xb)[row * 256 + t] = u;
    }
    float4 p; p.x = a0; p.y = a1; p.z = a2; p.w = a3;
    ((float4*)part)[bid * 256 + t] = p;
}

// Reduce part[1024][1024] -> xbar[4][1024]. 32 blocks, fully coalesced.
__global__ __launch_bounds__(256) void xbar_r(const float* __restrict__ part,
                                              float* __restrict__ xbar) {
    __shared__ float sl[256];
    int blk = blockIdx.x;            // 32 = b*8 + dgrp
    int b = blk >> 3, dgrp = blk & 7;
    int t = threadIdx.x;
    int col = dgrp * 128 + (t & 127);
    int ih = t >> 7;
    float s = 0.f;
    for (int i = 0; i < 128; ++i) {
        int cb = b * 256 + ih * 128 + i;
        s += part[cb * 1024 + col];
    }
    sl[t] = s;
    __syncthreads();
    if (t < 128) xbar[b * 1024 + col] = sl[t] + sl[t + 128];
}

// ---------------------------------------------------------------------------
// summary[b,h,k] = (1/S) * dot(xbar[b,:], W_proj[h,k,:]) * cos(pi*freq[h,k])
__global__ __launch_bounds__(256) void summary_k(const float* __restrict__ xbar,
                                                 const float* __restrict__ W,
                                                 const float* __restrict__ fr,
                                                 float* __restrict__ summary) {
    int wave = (blockIdx.x * 256 + threadIdx.x) >> 6;   // 0..4095 = b*1024+h*128+k
    int lane = threadIdx.x & 63;
    int b = wave >> 10, hk = wave & 1023;
    int h = hk >> 7, k = hk & 127;
    const float* wrow = &W[(h * 128 + k) << 10];
    const float* xrow = &xbar[b << 10];
    float s = 0.f;
    for (int d = lane; d < 1024; d += 64) s += xrow[d] * wrow[d];
    for (int off = 32; off; off >>= 1) s += __shfl_down(s, off);
    if (lane == 0) {
        float c = cosf(fr[h * 128 + k] * PI_F);
        summary[wave] = s * c * (1.0f / 4096.0f);
    }
}

// ---------------------------------------------------------------------------
// pol -> normalize -> dots -> gelu MLP -> softplus -> impedance & coef. 1 block.
__global__ __launch_bounds__(256) void imp_k(const float* __restrict__ summary,
                                             const float* __restrict__ pol_W,
                                             const float* __restrict__ pol_b,
                                             const float* __restrict__ imp_W1,
                                             const float* __restrict__ imp_b1,
                                             const float* __restrict__ imp_W2,
                                             const float* __restrict__ imp_b2,
                                             float* __restrict__ coef_out,
                                             float* __restrict__ imp_out) {
    __shared__ float pol[4][8][32];
    __shared__ float rn[32];
    int t = threadIdx.x;
    for (int o = t; o < 1024; o += 256) {
        int b = o >> 8, h = (o >> 5) & 7, p = o & 31;
        const float* srow = &summary[(b * 8 + h) * 128];
        const float* wrow = &pol_W[(h * 32 + p) * 128];
        float acc = pol_b[h * 32 + p];
        for (int k = 0; k < 128; ++k) acc += srow[k] * wrow[k];
        pol[b][h][p] = tanhf(acc);
    }
    __syncthreads();
    if (t < 32) {
        int b = t >> 3, h = t & 7;
        float ss = 0.f;
        for (int p = 0; p < 32; ++p) { float v = pol[b][h][p]; ss += v * v; }
        rn[t] = 1.0f / fmaxf(sqrtf(ss), 1e-12f);
    }
    __syncthreads();
    {
        int b = t >> 6, i = (t >> 3) & 7, j = t & 7;
        float d = 0.f;
        for (int p = 0; p < 32; ++p) d += pol[b][i][p] * pol[b][j][p];
        d *= rn[b * 8 + i] * rn[b * 8 + j];
        float s = imp_b2[0];
        for (int c = 0; c < 16; ++c) {
            float z = d * imp_W1[c] + imp_b1[c];
            float gl = 0.5f * z * (1.0f + erff(z * 0.70710678118654752f));
            s += gl * imp_W2[c];
        }
        float sp = fmaxf(s, 0.0f) + log1pf(expf(-fabsf(s)));   // softplus
        float impv = (i == j) ? 0.0f : sp;
        imp_out[t] = impv;
        coef_out[t] = (i == j) ? 0.0f : 0.1f / (1.0f + impv);
    }
}

// ---------------------------------------------------------------------------
// ===== 128x256 GEMM core: ring-2 single-barrier, 2 blocks/CU + big phases ==
//
// Experiment grid: {big phase, 1 blk/CU} (r1/r2: 55us, 22-24% Mfma), {small
// phase, 2 blk/CU} (r3: 99us, 14%), {medium, ~3 blk/CU} (r0: 64us, 22%).
// This is the unexplored cell: per-CU per-phase MFMA density EQUAL to r2
// (2 blk x 8 waves x 16 MFMA = 256) AND 2 independent blocks per CU so the
// per-phase vmcnt(0)+barrier of one block hides under the other's compute.
//
// 512 thr = 8 waves, wm=wid>>2 (2 row-halves), wn=wid&3 (4 col-quarters);
// per-wave out 64x64, acc[4][4].  LDS 48KB: A 2 slots x 8KB (128r x 32k),
// B 2 slots x 16KB (256r x 32k).  Phase p (0..31):
//   { VMCNT(0); s_barrier; issue 3x async16 (half p+1 -> slot (p+1)&1);
//     8x ds_read_b128 (slot p&1); 16x MFMA (setprio-wrapped) }
// Safety: stage(p+1) issues after ALL waves passed barrier(p), i.e. after
// every wave finished phase p-1 reads of slot (p+1)&1.  My phase-p reads of
// slot p&1 are covered because each wave drained its own loads (vmcnt 0)
// BEFORE barrier(p).  Stage->consume window = one full phase of ds/MFMA.
//
// LDS map (verified conflict-free in r3, SQ_LDS_BANK_CONFLICT=0): staging
// thread t writes byte (wid*16+(t&15), kc=(t>>4)&3) at wid*1024+kc*256+
// (t&15)*16; fragment read addr = subtile*1024 + q*256 + c16*16.
// ---------------------------------------------------------------------------
#define VMCNT(n) asm volatile("s_waitcnt vmcnt(" #n ")" ::: "memory")
#define SBAR() __builtin_amdgcn_s_barrier()

// XCD-contiguous swizzle for grid 512 (128 row-blocks x 4 col-blocks):
// each XCD (n&7) owns a contiguous 16-row-band slab; cols iterate slowest.
__device__ __forceinline__ void swz512(int n, long& rowBase, long& colBase) {
    int xcd = n & 7, s = n >> 3;                 // s in 0..63
    rowBase = (long)(xcd * 16 + (s & 15)) * 128;
    colBase = (long)(s >> 4) * 256;
}

// One phase: drain own loads, barrier, stage half p+1, 8 reads + 16 MFMA.
#define PH(p, DO_ST, KOFF)                                                   \
    {                                                                        \
        VMCNT(0);                                                            \
        SBAR();                                                              \
        if (DO_ST) {                                                         \
            async16(sA + (KOFF), stDstA + (((p) + 1) & 1) * 8192);           \
            async16(sB + (KOFF), stDstB + (((p) + 1) & 1) * 16384);          \
            async16(sB + (KOFF) + 262144,                                    \
                    stDstB + (((p) + 1) & 1) * 16384 + 8192);                \
        }                                                                    \
        const char* pA = rdA + ((p) & 1) * 8192;                             \
        const char* pB = rdB + ((p) & 1) * 16384;                            \
        bf16x8 af[4], bv[4];                                                 \
        _Pragma("unroll") for (int i_ = 0; i_ < 4; ++i_)                     \
            af[i_] = *(const bf16x8*)(pA + i_ * 1024);                       \
        _Pragma("unroll") for (int i_ = 0; i_ < 4; ++i_)                     \
            bv[i_] = *(const bf16x8*)(pB + i_ * 1024);                       \
        __builtin_amdgcn_s_setprio(1);                                       \
        _Pragma("unroll") for (int mi = 0; mi < 4; ++mi)                     \
            _Pragma("unroll") for (int ni = 0; ni < 4; ++ni)                 \
                acc[mi][ni] = __builtin_amdgcn_mfma_f32_16x16x32_bf16(       \
                    af[mi], bv[ni], acc[mi][ni], 0, 0, 0);                   \
        __builtin_amdgcn_s_setprio(0);                                       \
    }

__device__ __forceinline__ void gemm8_core(const char* gAB, const char* gBB,
                                           char* smem, const int t,
                                           f32x4 acc[4][4]) {
    const int l = t & 63, wid = t >> 6;          // 8 waves
    const int wm = wid >> 2, wn = wid & 3;
    // staging source: row = wid*16 + (t&15), k-chunk = ((t>>4)&3)*16B
    const long stOff = (long)((wid << 4) + (t & 15)) * 2048 + ((t >> 4) & 3) * 16;
    const char* sA = gAB + stOff;
    const char* sB = gBB + stOff;
    char* As = smem;                 // 2 slots x 8KB  (128 rows x 32 k)
    char* Bs = smem + 16384;         // 2 slots x 16KB (256 rows x 32 k)
    char* stDstA = As + wid * 1024;  // + slot*8192
    char* stDstB = Bs + wid * 1024;  // + slot*16384 (+8192 rows 128..255)
    const char* rdA = As + wm * 4096 + (l >> 4) * 256 + (l & 15) * 16;
    const char* rdB = Bs + wn * 4096 + (l >> 4) * 256 + (l & 15) * 16;

    // Prologue: stage half 0 into slot 0 (3 loads per wave in flight).
    async16(sA, stDstA);
    async16(sB, stDstB);
    async16(sB + 262144, stDstB + 8192);

    int kb = 64;                     // byte offset of half 1
    for (int grp = 0; grp < 15; ++grp) {   // phases 0..29 read halves 0..29
        PH(0, true, kb)
        PH(1, true, kb + 64)
        kb += 128;
    }
    PH(0, true, 1984)                // phase 30, stages half 31
    PH(1, false, 0)                  // phase 31
}

// ---------------------------------------------------------------------------
// GEMM1 + fused head-mix epilogue on the 128x256 tile.  Columns are
// (k,h)-interleaved; mix group = 8 consecutive cols (tile-local).
// 8 passes x 16-row slab (16x264 f32 = 16.9KB aliased over K-loop LDS;
// guarded by a __syncthreads after the core).
__global__ __launch_bounds__(512, 4) void gemm1_mix(
    const unsigned short* __restrict__ A, const unsigned short* __restrict__ B,
    const float* __restrict__ coef, const int* __restrict__ causal,
    unsigned short* __restrict__ C) {
    __shared__ char smem[49152];
    __shared__ float cfs[64];
    const int t = threadIdx.x;
    long rowBase, colBase;
    swz512(blockIdx.x, rowBase, colBase);
    const int b = (int)(rowBase >> 12);
    if (t < 64) cfs[t] = coef[b * 64 + t];
    const int causalv = causal[0];

    f32x4 acc[4][4] = {};
    gemm8_core((const char*)A + rowBase * 2048, (const char*)B + colBase * 2048,
               smem, t, acc);
    __syncthreads();                 // last phase's LDS reads vs slab writes

    const int l = t & 63, wid = t >> 6;
    const int wm = wid >> 2, wn = wid & 3;
    const int q = l >> 4, c16 = l & 15;
    float* slab = (float*)smem;      // 16 x 264 f32
    const int r16 = t >> 5, kg = t & 31;   // 16 rows x 32 kgroups = 512
#pragma unroll
    for (int p = 0; p < 8; ++p) {
        if (wm == (p >> 2)) {
            const int mi = p & 3;
#pragma unroll
            for (int ni = 0; ni < 4; ++ni)
#pragma unroll
                for (int r = 0; r < 4; ++r)
                    slab[(q * 4 + r) * 264 + wn * 64 + ni * 16 + c16] =
                        acc[mi][ni][r];
        }
        __syncthreads();
        const float* src = slab + r16 * 264 + kg * 8;
        float v[8];
#pragma unroll
        for (int j = 0; j < 8; ++j) v[j] = src[j];
        const long row = rowBase + p * 16 + r16;
        const float scale =
            causalv ? (float)((row & 4095) + 1) * (1.0f / 4096.0f) : 1.0f;
        us8 o;
#pragma unroll
        for (int i = 0; i < 8; ++i) {
            float ts = 0.f;
#pragma unroll
            for (int j = 0; j < 8; ++j) ts += cfs[i * 8 + j] * v[j];
            o[i] = f2bf(v[i] + scale * ts);
        }
        *(us8*)(C + row * 1024 + colBase + kg * 8) = o;
        __syncthreads();
    }
}

// ---------------------------------------------------------------------------
// Plain GEMM (second projection): C = A @ B^T, bf16 out.
__global__ __launch_bounds__(512, 4) void gemm_bt(const unsigned short* __restrict__ A,
                                                  const unsigned short* __restrict__ B,
                                                  unsigned short* __restrict__ C) {
    __shared__ char smem[49152];
    const int t = threadIdx.x;
    long rowBase, colBase;
    swz512(blockIdx.x, rowBase, colBase);

    f32x4 acc[4][4] = {};
    gemm8_core((const char*)A + rowBase * 2048, (const char*)B + colBase * 2048,
               smem, t, acc);

    const int l = t & 63, wid = t >> 6;
    const int wm = wid >> 2, wn = wid & 3;
    const int q = l >> 4, c16 = l & 15;
#pragma unroll
    for (int mi = 0; mi < 4; ++mi) {
#pragma unroll
        for (int ni = 0; ni < 4; ++ni) {
            long col = colBase + wn * 64 + ni * 16 + c16;
            long row0 = rowBase + wm * 64 + mi * 16 + q * 4;
#pragma unroll
            for (int r = 0; r < 4; ++r)
                C[(row0 + r) * 1024 + col] = f2bf(acc[mi][ni][r]);
        }
    }
}

// ---------------------------------------------------------------------------
// LayerNorm over D=1024: y = ypre + out_b + x; out = (y-mu)/sqrt(var+eps)*g+b
__global__ __launch_bounds__(256) void ln_k(const unsigned short* __restrict__ ypre,
                                            const float* __restrict__ x,
                                            const float* __restrict__ outb,
                                            const float* __restrict__ gam,
                                            const float* __restrict__ bet,
                                            float* __restrict__ out) {
    int row = blockIdx.x;       // 16384
    int t = threadIdx.x;        // 256, 4 elems each
    long base = (long)row * 1024 + t * 4;
    ushort4 yp = *(const ushort4*)(ypre + base);
    float4 xv = *(const float4*)(x + base);
    float4 bv = *(const float4*)(outb + t * 4);
    float y0 = bf2f(yp.x) + xv.x + bv.x;
    float y1 = bf2f(yp.y) + xv.y + bv.y;
    float y2 = bf2f(yp.z) + xv.z + bv.z;
    float y3 = bf2f(yp.w) + xv.w + bv.w;
    float s = y0 + y1 + y2 + y3;
    float ss = y0 * y0 + y1 * y1 + y2 * y2 + y3 * y3;
    for (int off = 32; off; off >>= 1) {
        s += __shfl_down(s, off);
        ss += __shfl_down(ss, off);
    }
    __shared__ float red[8];
    int wv = t >> 6, ln = t & 63;
    if (ln == 0) { red[wv] = s; red[4 + wv] = ss; }
    __syncthreads();
    float S1 = red[0] + red[1] + red[2] + red[3];
    float S2 = red[4] + red[5] + red[6] + red[7];
    float mu = S1 * (1.0f / 1024.0f);
    float var = S2 * (1.0f / 1024.0f) - mu * mu;
    float rs = 1.0f / sqrtf(var + 1e-5f);
    float4 gv = *(const float4*)(gam + t * 4);
    float4 bb = *(const float4*)(bet + t * 4);
    float4 o;
    o.x = (y0 - mu) * rs * gv.x + bb.x;
    o.y = (y1 - mu) * rs * gv.y + bb.y;
    o.z = (y2 - mu) * rs * gv.z + bb.z;
    o.w = (y3 - mu) * rs * gv.w + bb.w;
    *(float4*)(out + base) = o;
}

// ---------------------------------------------------------------------------
extern "C" void kernel_launch(void* const* d_in, const int* in_sizes, int n_in,
                              void* d_out, int out_size, void* d_ws, size_t ws_size,
                              hipStream_t stream) {
    const float* x       = (const float*)d_in[0];
    const float* W_proj  = (const float*)d_in[1];
    const float* freqs   = (const float*)d_in[2];
    const float* pol_W   = (const float*)d_in[3];
    const float* pol_b   = (const float*)d_in[4];
    const float* imp_W1  = (const float*)d_in[5];
    const float* imp_b1  = (const float*)d_in[6];
    const float* imp_W2  = (const float*)d_in[7];
    const float* imp_b2  = (const float*)d_in[8];
    const float* out_W   = (const float*)d_in[9];
    const float* out_b   = (const float*)d_in[10];
    const float* ln_g    = (const float*)d_in[11];
    const float* ln_b    = (const float*)d_in[12];
    const int*   causal  = (const int*)d_in[13];
    float* out = (float*)d_out;

    char* ws = (char*)d_ws;
    unsigned short* xb      = (unsigned short*)(ws + 0);          // 32MB, reused as ypre
    unsigned short* merged  = (unsigned short*)(ws + 33554432);   // 32MB
    unsigned short* w1b     = (unsigned short*)(ws + 67108864);   // 2MB
    unsigned short* wob     = (unsigned short*)(ws + 69206016);   // 2MB
    float* xbar             = (float*)(ws + 71303168);            // 16KB
    float* summary          = (float*)(ws + 71319552);            // 16KB
    float* coef             = (float*)(ws + 71335936);            // 1KB
    float* part             = (float*)merged;                     // 4MB, dead before gemm1_mix
    unsigned short* ypre    = xb;

    prep_k<<<8192, 256, 0, stream>>>(W_proj, freqs, out_W, w1b, wob);
    xbar_cast<<<1024, 256, 0, stream>>>(x, xb, part);
    xbar_r<<<32, 256, 0, stream>>>(part, xbar);
    summary_k<<<1024, 256, 0, stream>>>(xbar, W_proj, freqs, summary);
    imp_k<<<1, 256, 0, stream>>>(summary, pol_W, pol_b, imp_W1, imp_b1,
                                 imp_W2, imp_b2, coef, out + 16777216);
    gemm1_mix<<<512, 512, 0, stream>>>(xb, w1b, coef, causal, merged);
    gemm_bt<<<512, 512, 0, stream>>>(merged, wob, ypre);
    ln_k<<<16384, 256, 0, stream>>>(ypre, x, out_b, ln_g, ln_b, out);
}

// Round 5
// 305.263 us; speedup vs baseline: 1.1095x; 1.0340x over previous
//
#include <hip/hip_runtime.h>

typedef __bf16 bf16x8 __attribute__((ext_vector_type(8)));
typedef float f32x4 __attribute__((ext_vector_type(4)));
typedef unsigned short us8 __attribute__((ext_vector_type(8)));

#define PI_F 3.14159265358979323846f

__device__ __forceinline__ unsigned short f2bf(float f) {
    unsigned u = __float_as_uint(f);
    u += 0x7FFFu + ((u >> 16) & 1u);   // RNE
    return (unsigned short)(u >> 16);
}
__device__ __forceinline__ float bf2f(unsigned short h) {
    return __uint_as_float(((unsigned)h) << 16);
}

__device__ __forceinline__ void async16(const void* g, void* l) {
    __builtin_amdgcn_global_load_lds(
        (const __attribute__((address_space(1))) unsigned int*)g,
        (__attribute__((address_space(3))) unsigned int*)l, 16, 0, 0);
}

// ---------------------------------------------------------------------------
// Merged weight prep.
// idx < 1M : W1b[(k*8+h)*1024 + d] = bf16( W_proj[h,k,d] * cos(pi*freq[h,k]) )
// else     : Wob[n*1024 + (k*8+h)] = bf16( out_W[n, h*128+k] )
__global__ __launch_bounds__(256) void prep_k(const float* __restrict__ W,
                                              const float* __restrict__ fr,
                                              const float* __restrict__ Wo,
                                              unsigned short* __restrict__ W1b,
                                              unsigned short* __restrict__ Wob) {
    int idx = blockIdx.x * 256 + threadIdx.x;      // 2M
    if (idx < (1 << 20)) {
        int n = idx >> 10, d = idx & 1023;
        int k = n >> 3, h = n & 7;
        float c = cosf(fr[h * 128 + k] * PI_F);
        W1b[idx] = f2bf(W[((h * 128 + k) << 10) + d] * c);
    } else {
        int i2 = idx - (1 << 20);
        int n = i2 >> 10, dp = i2 & 1023;
        int k = dp >> 3, h = dp & 7;
        Wob[i2] = f2bf(Wo[(n << 10) + h * 128 + k]);
    }
}

// ---------------------------------------------------------------------------
// x -> bf16 cast + per-(b,d) partial column sums via PLAIN stores.
__global__ __launch_bounds__(256) void xbar_cast(const float* __restrict__ x,
                                                 unsigned short* __restrict__ xb,
                                                 float* __restrict__ part) {
    int bid = blockIdx.x;            // 1024
    int b = bid >> 8;
    int s0 = (bid & 255) * 16;
    int t = threadIdx.x;             // d4 index
    float a0 = 0.f, a1 = 0.f, a2 = 0.f, a3 = 0.f;
    for (int i = 0; i < 16; ++i) {
        long row = (long)b * 4096 + s0 + i;
        float4 v = ((const float4*)x)[row * 256 + t];
        a0 += v.x; a1 += v.y; a2 += v.z; a3 += v.w;
        ushort4 u;
        u.x = f2bf(v.x); u.y = f2bf(v.y); u.z = f2bf(v.z); u.w = f2bf(v.w);
        ((ushort4*)xb)[row * 256 + t] = u;
    }
    float4 p; p.x = a0; p.y = a1; p.z = a2; p.w = a3;
    ((float4*)part)[bid * 256 + t] = p;
}

// Reduce part[1024][1024] -> xbar[4][1024]. 32 blocks, fully coalesced.
__global__ __launch_bounds__(256) void xbar_r(const float* __restrict__ part,
                                              float* __restrict__ xbar) {
    __shared__ float sl[256];
    int blk = blockIdx.x;            // 32 = b*8 + dgrp
    int b = blk >> 3, dgrp = blk & 7;
    int t = threadIdx.x;
    int col = dgrp * 128 + (t & 127);
    int ih = t >> 7;
    float s = 0.f;
    for (int i = 0; i < 128; ++i) {
        int cb = b * 256 + ih * 128 + i;
        s += part[cb * 1024 + col];
    }
    sl[t] = s;
    __syncthreads();
    if (t < 128) xbar[b * 1024 + col] = sl[t] + sl[t + 128];
}

// ---------------------------------------------------------------------------
// summary[b,h,k] = (1/S) * dot(xbar[b,:], W_proj[h,k,:]) * cos(pi*freq[h,k])
__global__ __launch_bounds__(256) void summary_k(const float* __restrict__ xbar,
                                                 const float* __restrict__ W,
                                                 const float* __restrict__ fr,
                                                 float* __restrict__ summary) {
    int wave = (blockIdx.x * 256 + threadIdx.x) >> 6;   // 0..4095 = b*1024+h*128+k
    int lane = threadIdx.x & 63;
    int b = wave >> 10, hk = wave & 1023;
    int h = hk >> 7, k = hk & 127;
    const float* wrow = &W[(h * 128 + k) << 10];
    const float* xrow = &xbar[b << 10];
    float s = 0.f;
    for (int d = lane; d < 1024; d += 64) s += xrow[d] * wrow[d];
    for (int off = 32; off; off >>= 1) s += __shfl_down(s, off);
    if (lane == 0) {
        float c = cosf(fr[h * 128 + k] * PI_F);
        summary[wave] = s * c * (1.0f / 4096.0f);
    }
}

// ---------------------------------------------------------------------------
// pol -> normalize -> dots -> gelu MLP -> softplus -> impedance & coef. 1 block.
__global__ __launch_bounds__(256) void imp_k(const float* __restrict__ summary,
                                             const float* __restrict__ pol_W,
                                             const float* __restrict__ pol_b,
                                             const float* __restrict__ imp_W1,
                                             const float* __restrict__ imp_b1,
                                             const float* __restrict__ imp_W2,
                                             const float* __restrict__ imp_b2,
                                             float* __restrict__ coef_out,
                                             float* __restrict__ imp_out) {
    __shared__ float pol[4][8][32];
    __shared__ float rn[32];
    int t = threadIdx.x;
    for (int o = t; o < 1024; o += 256) {
        int b = o >> 8, h = (o >> 5) & 7, p = o & 31;
        const float* srow = &summary[(b * 8 + h) * 128];
        const float* wrow = &pol_W[(h * 32 + p) * 128];
        float acc = pol_b[h * 32 + p];
        for (int k = 0; k < 128; ++k) acc += srow[k] * wrow[k];
        pol[b][h][p] = tanhf(acc);
    }
    __syncthreads();
    if (t < 32) {
        int b = t >> 3, h = t & 7;
        float ss = 0.f;
        for (int p = 0; p < 32; ++p) { float v = pol[b][h][p]; ss += v * v; }
        rn[t] = 1.0f / fmaxf(sqrtf(ss), 1e-12f);
    }
    __syncthreads();
    {
        int b = t >> 6, i = (t >> 3) & 7, j = t & 7;
        float d = 0.f;
        for (int p = 0; p < 32; ++p) d += pol[b][i][p] * pol[b][j][p];
        d *= rn[b * 8 + i] * rn[b * 8 + j];
        float s = imp_b2[0];
        for (int c = 0; c < 16; ++c) {
            float z = d * imp_W1[c] + imp_b1[c];
            float gl = 0.5f * z * (1.0f + erff(z * 0.70710678118654752f));
            s += gl * imp_W2[c];
        }
        float sp = fmaxf(s, 0.0f) + log1pf(expf(-fabsf(s)));   // softplus
        float impv = (i == j) ? 0.0f : sp;
        imp_out[t] = impv;
        coef_out[t] = (i == j) ? 0.0f : 0.1f / (1.0f + impv);
    }
}

// ---------------------------------------------------------------------------
// ===== 256x256 / BK=64 faithful 8-phase template (m201/m248 structure) =====
//
// 512 thr = 8 waves (wm=wid>>2, wn=wid&3); per-wave out 128x64, acc[8][4].
// LDS 128KB = 2 K-tile dbufs x (A 32KB + B 32KB); half-tile = 128 rows x 64k
// = 16KB = 2 global_load_lds per thread.  Group (K-tile T, buf RB=T&1) =
// 4 phases; each phase stages EXACTLY ONE half-tile of T+1 into buf RB^1 and
// runs one 16-MFMA quadrant between two asm barriers:
//   ph1: [stage A-h0][VMCNT(2)][bar] rd A(mh0,ks0)+B(ks0) [16 MFMA][bar]
//   ph2: rd A(mh1,ks0) [stage A-h1][bar][16 MFMA][bar]
//   ph3: rd A(mh0,ks1)+B(ks1) [stage B-h0][bar][16 MFMA][bar]
//   ph4: rd A(mh1,ks1) [stage B-h1][bar][16 MFMA][bar]
// vmcnt ledger (steady state): entering ph1, tile T's 8 loads outstanding;
// ph1 issues 2 (T+1 A-h0), VMCNT(2) retires exactly tile T's 8 -> all reads
// of the group are confirmed at ph1's barrier; ph2-4 reads issue BEFORE
// their barrier (pinned by asm memory barriers).  A-halves get 3-4 phases of
// latency cover; B-h1 one phase (B = 2MB, L2-hot).  vmcnt is never drained
// to 0 mid-loop (T4); last group drains with VMCNT(0).
//
// LDS map (linear dest, SQ_LDS_BANK_CONFLICT=0 verified r3): half h, thread
// t, load j -> byte h*16384 + j*8192 + t*16 holds row h*128+j*64+(t>>7)*16+
// (t&15), k-chunk ((t>>4)&7)*16B.  Fragment read: sub*2048 + ks*1024 +
// (l>>4)*256 + (l&15)*16, sub = wm*8+mi (A) / wn*4+ni (B) -> lane-linear 1KB.
// ---------------------------------------------------------------------------
#define VMCNT(n) asm volatile("s_waitcnt vmcnt(" #n ")" ::: "memory")
#define ABAR() asm volatile("s_barrier" ::: "memory")

// XCD-contiguous swizzle for grid 256 (64 row-blocks x 4 col-blocks).
// Verified r1: FETCH 41 -> 24.8 MB.
__device__ __forceinline__ void swz256(int n, long& rowBase, long& colBase) {
    int xcd = n & 7, s = n >> 3;                 // s in 0..31
    rowBase = (long)(xcd * 8 + (s & 7)) * 256;
    colBase = (long)(s >> 3) * 256;
}

// Stage one 128-row x 64-k half-tile (16KB): 2 loads per thread.
#define STAGE(gsrc, ldst, h, ko)                                             \
    async16((gsrc) + (h) * 262144 + (ko), (ldst) + (h) * 16384);             \
    async16((gsrc) + (h) * 262144 + 131072 + (ko), (ldst) + (h) * 16384 + 8192);

#define RD_A(base, mi0, ks)                                                  \
    _Pragma("unroll") for (int i_ = 0; i_ < 4; ++i_)                         \
        af[i_] = *(const bf16x8*)((base) + ((mi0) + i_) * 2048 + (ks) * 1024);

#define RD_B(base, ks)                                                       \
    _Pragma("unroll") for (int i_ = 0; i_ < 4; ++i_)                         \
        bv[i_] = *(const bf16x8*)((base) + i_ * 2048 + (ks) * 1024);

#define MFMA16(m0)                                                           \
    __builtin_amdgcn_s_setprio(1);                                           \
    _Pragma("unroll") for (int mi = 0; mi < 4; ++mi)                         \
        _Pragma("unroll") for (int ni = 0; ni < 4; ++ni)                     \
            acc[(m0) + mi][ni] = __builtin_amdgcn_mfma_f32_16x16x32_bf16(    \
                af[mi], bv[ni], acc[(m0) + mi][ni], 0, 0, 0);                \
    __builtin_amdgcn_s_setprio(0);

// One K-tile group = 4 phases (see header comment).
#define GRP(RB, DO_ST, KO, VMW)                                              \
    {                                                                        \
        char* Ad = smem + ((RB) ^ 1) * 65536 + t * 16;                       \
        char* Bd = Ad + 32768;                                               \
        const char* Ar = smem + (RB) * 65536 + wm * 16384 + qoff;            \
        const char* Br = smem + (RB) * 65536 + 32768 + wn * 8192 + qoff;     \
        bf16x8 af[4], bv[4];                                                 \
        /* ph1 */                                                            \
        if (DO_ST) { STAGE(sA, Ad, 0, KO) }                                  \
        VMCNT(VMW); ABAR();                                                  \
        RD_A(Ar, 0, 0) RD_B(Br, 0)                                           \
        MFMA16(0) ABAR();                                                    \
        /* ph2 */                                                            \
        RD_A(Ar, 4, 0)                                                       \
        if (DO_ST) { STAGE(sA, Ad, 1, KO) }                                  \
        ABAR(); MFMA16(4) ABAR();                                            \
        /* ph3 */                                                            \
        RD_A(Ar, 0, 1) RD_B(Br, 1)                                           \
        if (DO_ST) { STAGE(sB, Bd, 0, KO) }                                  \
        ABAR(); MFMA16(0) ABAR();                                            \
        /* ph4 */                                                            \
        RD_A(Ar, 4, 1)                                                       \
        if (DO_ST) { STAGE(sB, Bd, 1, KO) }                                  \
        ABAR(); MFMA16(4) ABAR();                                            \
    }

__device__ __forceinline__ void gemm256_core(const char* gAB, const char* gBB,
                                             char* smem, const int t,
                                             f32x4 acc[8][4]) {
    const int l = t & 63, wid = t >> 6;
    const int wm = wid >> 2, wn = wid & 3;
    // staging source: row-local = j*64 + (t>>7)*16 + (t&15), kc = (t>>4)&7
    const long rowPart =
        (long)(((t >> 7) << 4) + (t & 15)) * 2048 + ((t >> 4) & 7) * 16;
    const char* sA = gAB + rowPart;
    const char* sB = gBB + rowPart;
    const int qoff = ((l >> 4) << 8) + (l & 15) * 16;

    {   // prologue: stage K-tile 0 -> buf0 (8 loads), no wait.
        char* Ad = smem + t * 16;
        char* Bd = Ad + 32768;
        STAGE(sA, Ad, 0, 0) STAGE(sA, Ad, 1, 0)
        STAGE(sB, Bd, 0, 0) STAGE(sB, Bd, 1, 0)
    }
    for (int it = 0; it < 15; ++it) {
        const int RB = it & 1;
        const long KO = (long)(it + 1) * 128;
        GRP(RB, true, KO, 2)
    }
    GRP(1, false, 0, 0)   // K-tile 15: no staging, drain.
}

// ---------------------------------------------------------------------------
// GEMM1 + fused head-mix epilogue on the 256x256 tile (r1/r2-verified).
// Columns (k,h)-interleaved; mix group = 8 consecutive cols.  8 passes x
// 32-row slab (32x264 f32 = 33.8KB aliased over K-loop LDS).
__global__ __launch_bounds__(512, 2) void gemm1_mix(
    const unsigned short* __restrict__ A, const unsigned short* __restrict__ B,
    const float* __restrict__ coef, const int* __restrict__ causal,
    unsigned short* __restrict__ C) {
    __shared__ char smem[131072];
    __shared__ float cfs[64];
    const int t = threadIdx.x;
    long rowBase, colBase;
    swz256(blockIdx.x, rowBase, colBase);
    const int b = (int)(rowBase >> 12);
    if (t < 64) cfs[t] = coef[b * 64 + t];
    const int causalv = causal[0];

    f32x4 acc[8][4] = {};
    gemm256_core((const char*)A + rowBase * 2048, (const char*)B + colBase * 2048,
                 smem, t, acc);
    __syncthreads();                 // last group's LDS reads vs slab writes

    const int l = t & 63, wid = t >> 6;
    const int wm = wid >> 2, wn = wid & 3;
    const int q = l >> 4, c16 = l & 15;
    float* slab = (float*)smem;      // 32 x 264 f32
#pragma unroll
    for (int p = 0; p < 8; ++p) {
        if (wm == (p >> 2)) {
            const int m0 = (p & 3) * 2;
#pragma unroll
            for (int m2 = 0; m2 < 2; ++m2)
#pragma unroll
                for (int ni = 0; ni < 4; ++ni)
#pragma unroll
                    for (int r = 0; r < 4; ++r)
                        slab[(m2 * 16 + q * 4 + r) * 264 + wn * 64 + ni * 16 + c16] =
                            acc[m0 + m2][ni][r];
        }
        __syncthreads();
#pragma unroll
        for (int gg = 0; gg < 2; ++gg) {
            const int g = t + gg * 512;          // 1024 = 32 rows x 32 kgroups
            const int row32 = g >> 5, kg = g & 31;
            const float* src = slab + row32 * 264 + kg * 8;
            float v[8];
#pragma unroll
            for (int j = 0; j < 8; ++j) v[j] = src[j];
            const long row = rowBase + p * 32 + row32;
            const float scale =
                causalv ? (float)((row & 4095) + 1) * (1.0f / 4096.0f) : 1.0f;
            us8 o;
#pragma unroll
            for (int i = 0; i < 8; ++i) {
                float ts = 0.f;
#pragma unroll
                for (int j = 0; j < 8; ++j) ts += cfs[i * 8 + j] * v[j];
                o[i] = f2bf(v[i] + scale * ts);
            }
            *(us8*)(C + row * 1024 + colBase + kg * 8) = o;
        }
        __syncthreads();
    }
}

// ---------------------------------------------------------------------------
// Plain GEMM (second projection): C = A @ B^T, bf16 out (r2-verified epilogue).
__global__ __launch_bounds__(512, 2) void gemm_bt(const unsigned short* __restrict__ A,
                                                  const unsigned short* __restrict__ B,
                                                  unsigned short* __restrict__ C) {
    __shared__ char smem[131072];
    const int t = threadIdx.x;
    long rowBase, colBase;
    swz256(blockIdx.x, rowBase, colBase);

    f32x4 acc[8][4] = {};
    gemm256_core((const char*)A + rowBase * 2048, (const char*)B + colBase * 2048,
                 smem, t, acc);

    const int l = t & 63, wid = t >> 6;
    const int wm = wid >> 2, wn = wid & 3;
    const int q = l >> 4, c16 = l & 15;
#pragma unroll
    for (int mi = 0; mi < 8; ++mi)
#pragma unroll
        for (int ni = 0; ni < 4; ++ni) {
            const long col = colBase + wn * 64 + ni * 16 + c16;
            const long row0 = rowBase + wm * 128 + mi * 16 + q * 4;
#pragma unroll
            for (int r = 0; r < 4; ++r)
                C[(row0 + r) * 1024 + col] = f2bf(acc[mi][ni][r]);
        }
}

// ---------------------------------------------------------------------------
// LayerNorm over D=1024: y = ypre + out_b + x; out = (y-mu)/sqrt(var+eps)*g+b
__global__ __launch_bounds__(256) void ln_k(const unsigned short* __restrict__ ypre,
                                            const float* __restrict__ x,
                                            const float* __restrict__ outb,
                                            const float* __restrict__ gam,
                                            const float* __restrict__ bet,
                                            float* __restrict__ out) {
    int row = blockIdx.x;       // 16384
    int t = threadIdx.x;        // 256, 4 elems each
    long base = (long)row * 1024 + t * 4;
    ushort4 yp = *(const ushort4*)(ypre + base);
    float4 xv = *(const float4*)(x + base);
    float4 bv = *(const float4*)(outb + t * 4);
    float y0 = bf2f(yp.x) + xv.x + bv.x;
    float y1 = bf2f(yp.y) + xv.y + bv.y;
    float y2 = bf2f(yp.z) + xv.z + bv.z;
    float y3 = bf2f(yp.w) + xv.w + bv.w;
    float s = y0 + y1 + y2 + y3;
    float ss = y0 * y0 + y1 * y1 + y2 * y2 + y3 * y3;
    for (int off = 32; off; off >>= 1) {
        s += __shfl_down(s, off);
        ss += __shfl_down(ss, off);
    }
    __shared__ float red[8];
    int wv = t >> 6, ln = t & 63;
    if (ln == 0) { red[wv] = s; red[4 + wv] = ss; }
    __syncthreads();
    float S1 = red[0] + red[1] + red[2] + red[3];
    float S2 = red[4] + red[5] + red[6] + red[7];
    float mu = S1 * (1.0f / 1024.0f);
    float var = S2 * (1.0f / 1024.0f) - mu * mu;
    float rs = 1.0f / sqrtf(var + 1e-5f);
    float4 gv = *(const float4*)(gam + t * 4);
    float4 bb = *(const float4*)(bet + t * 4);
    float4 o;
    o.x = (y0 - mu) * rs * gv.x + bb.x;
    o.y = (y1 - mu) * rs * gv.y + bb.y;
    o.z = (y2 - mu) * rs * gv.z + bb.z;
    o.w = (y3 - mu) * rs * gv.w + bb.w;
    *(float4*)(out + base) = o;
}

// ---------------------------------------------------------------------------
extern "C" void kernel_launch(void* const* d_in, const int* in_sizes, int n_in,
                              void* d_out, int out_size, void* d_ws, size_t ws_size,
                              hipStream_t stream) {
    const float* x       = (const float*)d_in[0];
    const float* W_proj  = (const float*)d_in[1];
    const float* freqs   = (const float*)d_in[2];
    const float* pol_W   = (const float*)d_in[3];
    const float* pol_b   = (const float*)d_in[4];
    const float* imp_W1  = (const float*)d_in[5];
    const float* imp_b1  = (const float*)d_in[6];
    const float* imp_W2  = (const float*)d_in[7];
    const float* imp_b2  = (const float*)d_in[8];
    const float* out_W   = (const float*)d_in[9];
    const float* out_b   = (const float*)d_in[10];
    const float* ln_g    = (const float*)d_in[11];
    const float* ln_b    = (const float*)d_in[12];
    const int*   causal  = (const int*)d_in[13];
    float* out = (float*)d_out;

    char* ws = (char*)d_ws;
    unsigned short* xb      = (unsigned short*)(ws + 0);          // 32MB, reused as ypre
    unsigned short* merged  = (unsigned short*)(ws + 33554432);   // 32MB
    unsigned short* w1b     = (unsigned short*)(ws + 67108864);   // 2MB
    unsigned short* wob     = (unsigned short*)(ws + 69206016);   // 2MB
    float* xbar             = (float*)(ws + 71303168);            // 16KB
    float* summary          = (float*)(ws + 71319552);            // 16KB
    float* coef             = (float*)(ws + 71335936);            // 1KB
    float* part             = (float*)merged;                     // 4MB, dead before gemm1_mix
    unsigned short* ypre    = xb;

    prep_k<<<8192, 256, 0, stream>>>(W_proj, freqs, out_W, w1b, wob);
    xbar_cast<<<1024, 256, 0, stream>>>(x, xb, part);
    xbar_r<<<32, 256, 0, stream>>>(part, xbar);
    summary_k<<<1024, 256, 0, stream>>>(xbar, W_proj, freqs, summary);
    imp_k<<<1, 256, 0, stream>>>(summary, pol_W, pol_b, imp_W1, imp_b1,
                                 imp_W2, imp_b2, coef, out + 16777216);
    gemm1_mix<<<256, 512, 0, stream>>>(xb, w1b, coef, causal, merged);
    gemm_bt<<<256, 512, 0, stream>>>(merged, wob, ypre);
    ln_k<<<16384, 256, 0, stream>>>(ypre, x, out_b, ln_g, ln_b, out);
}

// Round 6
// 282.217 us; speedup vs baseline: 1.2001x; 1.0817x over previous
//
#include <hip/hip_runtime.h>

typedef __bf16 bf16x8 __attribute__((ext_vector_type(8)));
typedef float f32x4 __attribute__((ext_vector_type(4)));
typedef unsigned short us8 __attribute__((ext_vector_type(8)));

#define PI_F 3.14159265358979323846f

__device__ __forceinline__ unsigned short f2bf(float f) {
    unsigned u = __float_as_uint(f);
    u += 0x7FFFu + ((u >> 16) & 1u);   // RNE
    return (unsigned short)(u >> 16);
}
__device__ __forceinline__ float bf2f(unsigned short h) {
    return __uint_as_float(((unsigned)h) << 16);
}

__device__ __forceinline__ void async16(const void* g, void* l) {
    __builtin_amdgcn_global_load_lds(
        (const __attribute__((address_space(1))) unsigned int*)g,
        (__attribute__((address_space(3))) unsigned int*)l, 16, 0, 0);
}

// ---------------------------------------------------------------------------
// Merged weight prep.
// idx < 1M : W1b[(k*8+h)*1024 + d] = bf16( W_proj[h,k,d] * cos(pi*freq[h,k]) )
// else     : Wob[n*1024 + (k*8+h)] = bf16( out_W[n, h*128+k] )
__global__ __launch_bounds__(256) void prep_k(const float* __restrict__ W,
                                              const float* __restrict__ fr,
                                              const float* __restrict__ Wo,
                                              unsigned short* __restrict__ W1b,
                                              unsigned short* __restrict__ Wob) {
    int idx = blockIdx.x * 256 + threadIdx.x;      // 2M
    if (idx < (1 << 20)) {
        int n = idx >> 10, d = idx & 1023;
        int k = n >> 3, h = n & 7;
        float c = cosf(fr[h * 128 + k] * PI_F);
        W1b[idx] = f2bf(W[((h * 128 + k) << 10) + d] * c);
    } else {
        int i2 = idx - (1 << 20);
        int n = i2 >> 10, dp = i2 & 1023;
        int k = dp >> 3, h = dp & 7;
        Wob[i2] = f2bf(Wo[(n << 10) + h * 128 + k]);
    }
}

// ---------------------------------------------------------------------------
// x -> bf16 cast + per-(b,d) partial column sums via PLAIN stores.
__global__ __launch_bounds__(256) void xbar_cast(const float* __restrict__ x,
                                                 unsigned short* __restrict__ xb,
                                                 float* __restrict__ part) {
    int bid = blockIdx.x;            // 1024
    int b = bid >> 8;
    int s0 = (bid & 255) * 16;
    int t = threadIdx.x;             // d4 index
    float a0 = 0.f, a1 = 0.f, a2 = 0.f, a3 = 0.f;
    for (int i = 0; i < 16; ++i) {
        long row = (long)b * 4096 + s0 + i;
        float4 v = ((const float4*)x)[row * 256 + t];
        a0 += v.x; a1 += v.y; a2 += v.z; a3 += v.w;
        ushort4 u;
        u.x = f2bf(v.x); u.y = f2bf(v.y); u.z = f2bf(v.z); u.w = f2bf(v.w);
        ((ushort4*)xb)[row * 256 + t] = u;
    }
    float4 p; p.x = a0; p.y = a1; p.z = a2; p.w = a3;
    ((float4*)part)[bid * 256 + t] = p;
}

// Reduce part[1024][1024] -> xbar[4][1024]. 32 blocks, fully coalesced.
__global__ __launch_bounds__(256) void xbar_r(const float* __restrict__ part,
                                              float* __restrict__ xbar) {
    __shared__ float sl[256];
    int blk = blockIdx.x;            // 32 = b*8 + dgrp
    int b = blk >> 3, dgrp = blk & 7;
    int t = threadIdx.x;
    int col = dgrp * 128 + (t & 127);
    int ih = t >> 7;
    float s = 0.f;
    for (int i = 0; i < 128; ++i) {
        int cb = b * 256 + ih * 128 + i;
        s += part[cb * 1024 + col];
    }
    sl[t] = s;
    __syncthreads();
    if (t < 128) xbar[b * 1024 + col] = sl[t] + sl[t + 128];
}

// ---------------------------------------------------------------------------
// summary[b,h,k] = (1/S) * dot(xbar[b,:], W_proj[h,k,:]) * cos(pi*freq[h,k])
__global__ __launch_bounds__(256) void summary_k(const float* __restrict__ xbar,
                                                 const float* __restrict__ W,
                                                 const float* __restrict__ fr,
                                                 float* __restrict__ summary) {
    int wave = (blockIdx.x * 256 + threadIdx.x) >> 6;   // 0..4095 = b*1024+h*128+k
    int lane = threadIdx.x & 63;
    int b = wave >> 10, hk = wave & 1023;
    int h = hk >> 7, k = hk & 127;
    const float* wrow = &W[(h * 128 + k) << 10];
    const float* xrow = &xbar[b << 10];
    float s = 0.f;
    for (int d = lane; d < 1024; d += 64) s += xrow[d] * wrow[d];
    for (int off = 32; off; off >>= 1) s += __shfl_down(s, off);
    if (lane == 0) {
        float c = cosf(fr[h * 128 + k] * PI_F);
        summary[wave] = s * c * (1.0f / 4096.0f);
    }
}

// ---------------------------------------------------------------------------
// pol -> normalize -> dots -> gelu MLP -> softplus -> impedance & coef. 1 block.
__global__ __launch_bounds__(256) void imp_k(const float* __restrict__ summary,
                                             const float* __restrict__ pol_W,
                                             const float* __restrict__ pol_b,
                                             const float* __restrict__ imp_W1,
                                             const float* __restrict__ imp_b1,
                                             const float* __restrict__ imp_W2,
                                             const float* __restrict__ imp_b2,
                                             float* __restrict__ coef_out,
                                             float* __restrict__ imp_out) {
    __shared__ float pol[4][8][32];
    __shared__ float rn[32];
    int t = threadIdx.x;
    for (int o = t; o < 1024; o += 256) {
        int b = o >> 8, h = (o >> 5) & 7, p = o & 31;
        const float* srow = &summary[(b * 8 + h) * 128];
        const float* wrow = &pol_W[(h * 32 + p) * 128];
        float acc = pol_b[h * 32 + p];
        for (int k = 0; k < 128; ++k) acc += srow[k] * wrow[k];
        pol[b][h][p] = tanhf(acc);
    }
    __syncthreads();
    if (t < 32) {
        int b = t >> 3, h = t & 7;
        float ss = 0.f;
        for (int p = 0; p < 32; ++p) { float v = pol[b][h][p]; ss += v * v; }
        rn[t] = 1.0f / fmaxf(sqrtf(ss), 1e-12f);
    }
    __syncthreads();
    {
        int b = t >> 6, i = (t >> 3) & 7, j = t & 7;
        float d = 0.f;
        for (int p = 0; p < 32; ++p) d += pol[b][i][p] * pol[b][j][p];
        d *= rn[b * 8 + i] * rn[b * 8 + j];
        float s = imp_b2[0];
        for (int c = 0; c < 16; ++c) {
            float z = d * imp_W1[c] + imp_b1[c];
            float gl = 0.5f * z * (1.0f + erff(z * 0.70710678118654752f));
            s += gl * imp_W2[c];
        }
        float sp = fmaxf(s, 0.0f) + log1pf(expf(-fabsf(s)));   // softplus
        float impv = (i == j) ? 0.0f : sp;
        imp_out[t] = impv;
        coef_out[t] = (i == j) ? 0.0f : 0.1f / (1.0f + impv);
    }
}

// ---------------------------------------------------------------------------
// ===== 256x256 GEMM core: r2 ring-4 schedule + COALESCED staging map =======
//
// r0-r5: five schedules all pinned at 22% MfmaUtil.  Shared invariant: the
// staging source map row(l&15)*2048 + chunk(l>>4)*16 makes each
// global_load_lds instruction issue 64 SEPARATE 16B segments (adjacent lanes
// 2KB apart) -> ~65K segment-requests per block saturates the per-CU VMEM
// request path (~0.5 seg/cyc ~= the whole 55us).  Fix: permute the GLOBAL
// source (LDS dest stays hardware-linear, rule #21): 4-lane groups fetch one
// contiguous 64B row-chunk (16x fewer+4x larger segments), with chunk index
// XOR-folded by (row>>1)&3 so the matching swizzled ds_read_b128 is 2-way
// bank-aliased (free, m136).
//
// Maps (verified by hand):
//   stage: wave w, lane l, half j: row = j*128 + w*16 + (l>>2),
//          global chunk = (l&3) ^ ((l>>3)&3); LDS dest = linear l*16.
//   image: within j-half, offset wsrc*1024 + r16*64 + p*16 holds global
//          chunk p ^ ((r16>>1)&3) of row j*128 + wsrc*16 + r16.
//   read:  lane L, subtile row base 16-aligned: addr = sub*1024 +
//          (L&15)*64 + ((L>>4)^((L>>1)&3))*16 -> each 16B bank-slot hit by
//          exactly 2 lanes.  Fragment offsets (+i*1024) identical to r2.
// Schedule (unchanged from r2, best measured 55.0us): ring-4 slots, ONE
// barrier per phase, VMCNT(8) counted, never 0 mid-loop; setprio around MFMA.
// ---------------------------------------------------------------------------
#define VMCNT(n) asm volatile("s_waitcnt vmcnt(" #n ")" ::: "memory")
#define SBAR() __builtin_amdgcn_s_barrier()

// XCD-contiguous swizzle for grid 256 (64 row-blocks x 4 col-blocks).
// Verified r1: FETCH 41 -> 24.8 MB.
__device__ __forceinline__ void swz256(int n, long& rowBase, long& colBase) {
    int xcd = n & 7, s = n >> 3;                 // s in 0..31
    rowBase = (long)(xcd * 8 + (s & 7)) * 256;
    colBase = (long)(s >> 3) * 256;
}

#define STG(sPtr, dPtr, koff, slot)                                          \
    async16((sPtr) + (koff), (dPtr) + (slot) * 16384);                       \
    async16((sPtr) + (koff) + 262144, (dPtr) + (slot) * 16384 + 8192);

// One phase: stage half p+2, counted wait, barrier, 12 reads + 32 MFMA.
#define PH(p, DO_ST, KOFF, VM)                                               \
    {                                                                        \
        if (DO_ST) {                                                         \
            STG(sA, stDstA, (KOFF), ((p) + 2) & 3)                           \
            STG(sB, stDstB, (KOFF), ((p) + 2) & 3)                           \
        }                                                                    \
        VM;                                                                  \
        SBAR();                                                              \
        const char* pA = rdA + ((p) & 3) * 16384;                            \
        const char* pB = rdB + ((p) & 3) * 16384;                            \
        bf16x8 af[4], bv[4];                                                 \
        _Pragma("unroll") for (int i_ = 0; i_ < 4; ++i_)                     \
            af[i_] = *(const bf16x8*)(pA + i_ * 1024);                       \
        _Pragma("unroll") for (int i_ = 0; i_ < 4; ++i_)                     \
            bv[i_] = *(const bf16x8*)(pB + i_ * 1024);                       \
        __builtin_amdgcn_s_setprio(1);                                       \
        _Pragma("unroll") for (int mi = 0; mi < 4; ++mi)                     \
            _Pragma("unroll") for (int ni = 0; ni < 4; ++ni)                 \
                acc[mi][ni] = __builtin_amdgcn_mfma_f32_16x16x32_bf16(       \
                    af[mi], bv[ni], acc[mi][ni], 0, 0, 0);                   \
        __builtin_amdgcn_s_setprio(0);                                       \
        _Pragma("unroll") for (int i_ = 0; i_ < 4; ++i_)                     \
            af[i_] = *(const bf16x8*)(pA + (4 + i_) * 1024);                 \
        __builtin_amdgcn_s_setprio(1);                                       \
        _Pragma("unroll") for (int mi = 0; mi < 4; ++mi)                     \
            _Pragma("unroll") for (int ni = 0; ni < 4; ++ni)                 \
                acc[4 + mi][ni] = __builtin_amdgcn_mfma_f32_16x16x32_bf16(   \
                    af[mi], bv[ni], acc[4 + mi][ni], 0, 0, 0);               \
        __builtin_amdgcn_s_setprio(0);                                       \
    }

__device__ __forceinline__ void gemm8_core(const char* gAB, const char* gBB,
                                           char* smem, const int t,
                                           f32x4 acc[8][4]) {
    const int l = t & 63, wid = t >> 6;
    const int wm = wid >> 2, wn = wid & 3;
    // COALESCED staging source: row = wid*16 + (l>>2) (4-lane groups share a
    // row -> one 64B segment), chunk = (l&3) ^ ((l>>3)&3) (read-swizzle fold).
    const long stOff =
        (long)((wid << 4) + (l >> 2)) * 2048 + (((l & 3) ^ ((l >> 3) & 3)) * 16);
    const char* sA = gAB + stOff;
    const char* sB = gBB + stOff;
    char* As = smem;                 // 4 slots x 16KB
    char* Bs = smem + 65536;         // 4 slots x 16KB
    char* stDstA = As + wid * 1024;  // + slot*16384 (+8192 rows 128..255)
    char* stDstB = Bs + wid * 1024;
    // Swizzled fragment-read lane offset: (l&15)*64 + ((l>>4)^((l>>1)&3))*16.
    const int lsw = (l & 15) * 64 + ((((l >> 4) ^ ((l >> 1) & 3))) * 16);
    const char* rdA = As + wm * 8192 + lsw;   // + slot*16384 + sub*1024
    const char* rdB = Bs + wn * 4096 + lsw;   // + slot*16384 + sub*1024

    // Prologue: stage halves 0 and 1 (8 loads in flight).
    STG(sA, stDstA, 0, 0)
    STG(sB, stDstB, 0, 0)
    STG(sA, stDstA, 64, 1)
    STG(sB, stDstB, 64, 1)

    int kb = 128;                    // byte offset of half 2
    for (int grp = 0; grp < 7; ++grp) {   // phases 0..27
        PH(0, true, kb, VMCNT(8))
        PH(1, true, kb + 64, VMCNT(8))
        PH(2, true, kb + 128, VMCNT(8))
        PH(3, true, kb + 192, VMCNT(8))
        kb += 256;
    }
    PH(0, true, 1920, VMCNT(8))      // g=28, stages half 30
    PH(1, true, 1984, VMCNT(8))      // g=29, stages half 31
    PH(2, false, 0, VMCNT(4))        // g=30 (drain stage 30)
    PH(3, false, 0, VMCNT(0))        // g=31 (drain stage 31)
}

// ---------------------------------------------------------------------------
// GEMM1 + fused head-mix epilogue on the 256x256 tile (r2-verified).
// Columns (k,h)-interleaved; mix group = 8 consecutive cols.  8 passes x
// 32-row slab (32x264 f32 = 33.8KB aliased over K-loop LDS).
__global__ __launch_bounds__(512, 2) void gemm1_mix(
    const unsigned short* __restrict__ A, const unsigned short* __restrict__ B,
    const float* __restrict__ coef, const int* __restrict__ causal,
    unsigned short* __restrict__ C) {
    __shared__ char smem[131072];
    __shared__ float cfs[64];
    const int t = threadIdx.x;
    long rowBase, colBase;
    swz256(blockIdx.x, rowBase, colBase);
    const int b = (int)(rowBase >> 12);
    if (t < 64) cfs[t] = coef[b * 64 + t];
    const int causalv = causal[0];

    f32x4 acc[8][4] = {};
    gemm8_core((const char*)A + rowBase * 2048, (const char*)B + colBase * 2048,
               smem, t, acc);
    __syncthreads();                 // last phase's LDS reads vs slab writes

    const int l = t & 63, wid = t >> 6;
    const int wm = wid >> 2, wn = wid & 3;
    const int q = l >> 4, c16 = l & 15;
    float* slab = (float*)smem;      // 32 x 264 f32
#pragma unroll
    for (int p = 0; p < 8; ++p) {
        if (wm == (p >> 2)) {
            const int m0 = (p & 3) * 2;
#pragma unroll
            for (int m2 = 0; m2 < 2; ++m2)
#pragma unroll
                for (int ni = 0; ni < 4; ++ni)
#pragma unroll
                    for (int r = 0; r < 4; ++r)
                        slab[(m2 * 16 + q * 4 + r) * 264 + wn * 64 + ni * 16 + c16] =
                            acc[m0 + m2][ni][r];
        }
        __syncthreads();
#pragma unroll
        for (int gg = 0; gg < 2; ++gg) {
            const int g = t + gg * 512;          // 1024 = 32 rows x 32 kgroups
            const int row32 = g >> 5, kg = g & 31;
            const float* src = slab + row32 * 264 + kg * 8;
            float v[8];
#pragma unroll
            for (int j = 0; j < 8; ++j) v[j] = src[j];
            const long row = rowBase + p * 32 + row32;
            const float scale =
                causalv ? (float)((row & 4095) + 1) * (1.0f / 4096.0f) : 1.0f;
            us8 o;
#pragma unroll
            for (int i = 0; i < 8; ++i) {
                float ts = 0.f;
#pragma unroll
                for (int j = 0; j < 8; ++j) ts += cfs[i * 8 + j] * v[j];
                o[i] = f2bf(v[i] + scale * ts);
            }
            *(us8*)(C + row * 1024 + colBase + kg * 8) = o;
        }
        __syncthreads();
    }
}

// ---------------------------------------------------------------------------
// Plain GEMM (second projection): C = A @ B^T, bf16 out (r2-verified epilogue).
__global__ __launch_bounds__(512, 2) void gemm_bt(const unsigned short* __restrict__ A,
                                                  const unsigned short* __restrict__ B,
                                                  unsigned short* __restrict__ C) {
    __shared__ char smem[131072];
    const int t = threadIdx.x;
    long rowBase, colBase;
    swz256(blockIdx.x, rowBase, colBase);

    f32x4 acc[8][4] = {};
    gemm8_core((const char*)A + rowBase * 2048, (const char*)B + colBase * 2048,
               smem, t, acc);

    const int l = t & 63, wid = t >> 6;
    const int wm = wid >> 2, wn = wid & 3;
    const int q = l >> 4, c16 = l & 15;
#pragma unroll
    for (int mi = 0; mi < 8; ++mi)
#pragma unroll
        for (int ni = 0; ni < 4; ++ni) {
            const long col = colBase + wn * 64 + ni * 16 + c16;
            const long row0 = rowBase + wm * 128 + mi * 16 + q * 4;
#pragma unroll
            for (int r = 0; r < 4; ++r)
                C[(row0 + r) * 1024 + col] = f2bf(acc[mi][ni][r]);
        }
}

// ---------------------------------------------------------------------------
// LayerNorm over D=1024: y = ypre + out_b + x; out = (y-mu)/sqrt(var+eps)*g+b
__global__ __launch_bounds__(256) void ln_k(const unsigned short* __restrict__ ypre,
                                            const float* __restrict__ x,
                                            const float* __restrict__ outb,
                                            const float* __restrict__ gam,
                                            const float* __restrict__ bet,
                                            float* __restrict__ out) {
    int row = blockIdx.x;       // 16384
    int t = threadIdx.x;        // 256, 4 elems each
    long base = (long)row * 1024 + t * 4;
    ushort4 yp = *(const ushort4*)(ypre + base);
    float4 xv = *(const float4*)(x + base);
    float4 bv = *(const float4*)(outb + t * 4);
    float y0 = bf2f(yp.x) + xv.x + bv.x;
    float y1 = bf2f(yp.y) + xv.y + bv.y;
    float y2 = bf2f(yp.z) + xv.z + bv.z;
    float y3 = bf2f(yp.w) + xv.w + bv.w;
    float s = y0 + y1 + y2 + y3;
    float ss = y0 * y0 + y1 * y1 + y2 * y2 + y3 * y3;
    for (int off = 32; off; off >>= 1) {
        s += __shfl_down(s, off);
        ss += __shfl_down(ss, off);
    }
    __shared__ float red[8];
    int wv = t >> 6, ln = t & 63;
    if (ln == 0) { red[wv] = s; red[4 + wv] = ss; }
    __syncthreads();
    float S1 = red[0] + red[1] + red[2] + red[3];
    float S2 = red[4] + red[5] + red[6] + red[7];
    float mu = S1 * (1.0f / 1024.0f);
    float var = S2 * (1.0f / 1024.0f) - mu * mu;
    float rs = 1.0f / sqrtf(var + 1e-5f);
    float4 gv = *(const float4*)(gam + t * 4);
    float4 bb = *(const float4*)(bet + t * 4);
    float4 o;
    o.x = (y0 - mu) * rs * gv.x + bb.x;
    o.y = (y1 - mu) * rs * gv.y + bb.y;
    o.z = (y2 - mu) * rs * gv.z + bb.z;
    o.w = (y3 - mu) * rs * gv.w + bb.w;
    *(float4*)(out + base) = o;
}

// ---------------------------------------------------------------------------
extern "C" void kernel_launch(void* const* d_in, const int* in_sizes, int n_in,
                              void* d_out, int out_size, void* d_ws, size_t ws_size,
                              hipStream_t stream) {
    const float* x       = (const float*)d_in[0];
    const float* W_proj  = (const float*)d_in[1];
    const float* freqs   = (const float*)d_in[2];
    const float* pol_W   = (const float*)d_in[3];
    const float* pol_b   = (const float*)d_in[4];
    const float* imp_W1  = (const float*)d_in[5];
    const float* imp_b1  = (const float*)d_in[6];
    const float* imp_W2  = (const float*)d_in[7];
    const float* imp_b2  = (const float*)d_in[8];
    const float* out_W   = (const float*)d_in[9];
    const float* out_b   = (const float*)d_in[10];
    const float* ln_g    = (const float*)d_in[11];
    const float* ln_b    = (const float*)d_in[12];
    const int*   causal  = (const int*)d_in[13];
    float* out = (float*)d_out;

    char* ws = (char*)d_ws;
    unsigned short* xb      = (unsigned short*)(ws + 0);          // 32MB, reused as ypre
    unsigned short* merged  = (unsigned short*)(ws + 33554432);   // 32MB
    unsigned short* w1b     = (unsigned short*)(ws + 67108864);   // 2MB
    unsigned short* wob     = (unsigned short*)(ws + 69206016);   // 2MB
    float* xbar             = (float*)(ws + 71303168);            // 16KB
    float* summary          = (float*)(ws + 71319552);            // 16KB
    float* coef             = (float*)(ws + 71335936);            // 1KB
    float* part             = (float*)merged;                     // 4MB, dead before gemm1_mix
    unsigned short* ypre    = xb;

    prep_k<<<8192, 256, 0, stream>>>(W_proj, freqs, out_W, w1b, wob);
    xbar_cast<<<1024, 256, 0, stream>>>(x, xb, part);
    xbar_r<<<32, 256, 0, stream>>>(part, xbar);
    summary_k<<<1024, 256, 0, stream>>>(xbar, W_proj, freqs, summary);
    imp_k<<<1, 256, 0, stream>>>(summary, pol_W, pol_b, imp_W1, imp_b1,
                                 imp_W2, imp_b2, coef, out + 16777216);
    gemm1_mix<<<256, 512, 0, stream>>>(xb, w1b, coef, causal, merged);
    gemm_bt<<<256, 512, 0, stream>>>(merged, wob, ypre);
    ln_k<<<16384, 256, 0, stream>>>(ypre, x, out_b, ln_g, ln_b, out);
}